// Round 1
// baseline (524.570 us; speedup 1.0000x reference)
//
#include <hip/hip_runtime.h>

#define B_ 4096
#define T_ 512
#define F_ 8
#define H_ 16

// sigmoid via v_exp_f32 + v_rcp_f32 (both ~1ulp; threshold is 6.4e-3 so fine)
__device__ __forceinline__ float sigf(float v) {
    return __builtin_amdgcn_rcpf(1.0f + __expf(-v));
}
// tanh(x) = 2*sigmoid(2x) - 1 (saturates correctly: exp->inf -> rcp->0 -> -1)
__device__ __forceinline__ float tanh_f(float v) {
    return 2.0f * __builtin_amdgcn_rcpf(1.0f + __expf(-2.0f * v)) - 1.0f;
}

// Layout: 16 lanes per batch element (lane j owns h_j, c_j and gate rows j,
// j+16, j+32, j+48 of the weight matrices). 4 batch elements per wave,
// 16 per 256-thread block, 256 blocks -> 4096 batch chains, 1024 waves.
// h broadcast per step goes through a group-private LDS slot (same wave ->
// lockstep -> no __syncthreads; __builtin_amdgcn_wave_barrier pins ordering).
__global__ __launch_bounds__(256, 1) void lstm_ae_kernel(
    const float* __restrict__ x,
    const float* __restrict__ eWih, const float* __restrict__ eWhh,
    const float* __restrict__ ebih, const float* __restrict__ ebhh,
    const float* __restrict__ dWih, const float* __restrict__ dWhh,
    const float* __restrict__ dbih, const float* __restrict__ dbhh,
    const float* __restrict__ oW,   const float* __restrict__ ob,
    float* __restrict__ out)
{
    const int tid = threadIdx.x;
    const int grp = tid >> 4;   // group (batch element) within block, 0..15
    const int j   = tid & 15;   // hidden unit owned by this lane
    const int b   = blockIdx.x * 16 + grp;

    // row stride 20 floats: groups 0..3 of a wave land on disjoint bank sets
    __shared__ __align__(16) float hbuf[16][20];
    // 32 timesteps * 8 feats staged per group; stride 264 breaks 4-way aliasing
    __shared__ __align__(16) float xsh[16][264];

    // ---------------- encoder weights (registers) ----------------
    float wh[4][16], wi[4][8], bias[4];
#pragma unroll
    for (int q = 0; q < 4; ++q) {
        const int row = q * 16 + j;
#pragma unroll
        for (int k = 0; k < 16; k += 4) {
            const float4 v = *(const float4*)(eWhh + row * 16 + k);
            wh[q][k] = v.x; wh[q][k+1] = v.y; wh[q][k+2] = v.z; wh[q][k+3] = v.w;
        }
#pragma unroll
        for (int k = 0; k < 8; k += 4) {
            const float4 v = *(const float4*)(eWih + row * 8 + k);
            wi[q][k] = v.x; wi[q][k+1] = v.y; wi[q][k+2] = v.z; wi[q][k+3] = v.w;
        }
        bias[q] = ebih[row] + ebhh[row];
    }

    float h = 0.0f, c = 0.0f;
    hbuf[grp][j] = 0.0f;
    __builtin_amdgcn_wave_barrier();

    const float* xb = x + (size_t)b * (T_ * F_);

    // ---------------- encoder ----------------
    for (int c0 = 0; c0 < T_; c0 += 32) {
        // stage 32 steps of x (256 floats) for this group: 16 lanes * 4 float4
#pragma unroll
        for (int q = 0; q < 4; ++q) {
            const float4 v = *(const float4*)(xb + c0 * F_ + (q * 16 + j) * 4);
            *(float4*)&xsh[grp][(q * 16 + j) * 4] = v;
        }
        __builtin_amdgcn_wave_barrier();
        for (int s = 0; s < 32; ++s) {
            float hb[16];
#pragma unroll
            for (int k = 0; k < 16; k += 4) {
                const float4 v = *(const float4*)&hbuf[grp][k];
                hb[k] = v.x; hb[k+1] = v.y; hb[k+2] = v.z; hb[k+3] = v.w;
            }
            float xv[8];
#pragma unroll
            for (int k = 0; k < 8; k += 4) {
                const float4 v = *(const float4*)&xsh[grp][s * F_ + k];
                xv[k] = v.x; xv[k+1] = v.y; xv[k+2] = v.z; xv[k+3] = v.w;
            }
            float acc0 = bias[0], acc1 = bias[1], acc2 = bias[2], acc3 = bias[3];
#pragma unroll
            for (int k = 0; k < 8; ++k) {
                acc0 += wi[0][k] * xv[k];
                acc1 += wi[1][k] * xv[k];
                acc2 += wi[2][k] * xv[k];
                acc3 += wi[3][k] * xv[k];
            }
#pragma unroll
            for (int k = 0; k < 16; ++k) {
                acc0 += wh[0][k] * hb[k];
                acc1 += wh[1][k] * hb[k];
                acc2 += wh[2][k] * hb[k];
                acc3 += wh[3][k] * hb[k];
            }
            const float ig = sigf(acc0);
            const float fg = sigf(acc1);
            const float gg = tanh_f(acc2);
            const float og = sigf(acc3);
            c = fg * c + ig * gg;
            h = og * tanh_f(c);
            __builtin_amdgcn_wave_barrier();
            hbuf[grp][j] = h;
            __builtin_amdgcn_wave_barrier();
        }
    }

    // hT broadcast currently sits in hbuf
    float hT[16];
#pragma unroll
    for (int k = 0; k < 16; k += 4) {
        const float4 v = *(const float4*)&hbuf[grp][k];
        hT[k] = v.x; hT[k+1] = v.y; hT[k+2] = v.z; hT[k+3] = v.w;
    }

    // ---------------- decoder weights + constant input projection ----------
    float wd[4][16], xp[4];
#pragma unroll
    for (int q = 0; q < 4; ++q) {
        const int row = q * 16 + j;
        float a = dbih[row] + dbhh[row];
#pragma unroll
        for (int k = 0; k < 16; k += 4) {
            const float4 v = *(const float4*)(dWih + row * 16 + k);
            a += v.x * hT[k] + v.y * hT[k+1] + v.z * hT[k+2] + v.w * hT[k+3];
        }
        xp[q] = a;
#pragma unroll
        for (int k = 0; k < 16; k += 4) {
            const float4 v = *(const float4*)(dWhh + row * 16 + k);
            wd[q][k] = v.x; wd[q][k+1] = v.y; wd[q][k+2] = v.z; wd[q][k+3] = v.w;
        }
    }
    float wo[16];
    {
        const int r = j & 7;
#pragma unroll
        for (int k = 0; k < 16; k += 4) {
            const float4 v = *(const float4*)(oW + r * 16 + k);
            wo[k] = v.x; wo[k+1] = v.y; wo[k+2] = v.z; wo[k+3] = v.w;
        }
    }
    const float obv = ob[j & 7];

    h = 0.0f; c = 0.0f;
    __builtin_amdgcn_wave_barrier();
    hbuf[grp][j] = 0.0f;
    __builtin_amdgcn_wave_barrier();

    float* outp = out + (size_t)b * (T_ * F_);

    // ---------------- decoder + fused output projection ----------------
    // out for step t is computed at iteration t+1 from the h_t broadcast
    for (int t = 0; t < T_; ++t) {
        float hb[16];
#pragma unroll
        for (int k = 0; k < 16; k += 4) {
            const float4 v = *(const float4*)&hbuf[grp][k];
            hb[k] = v.x; hb[k+1] = v.y; hb[k+2] = v.z; hb[k+3] = v.w;
        }
        if (t > 0) {
            float oa = obv;
#pragma unroll
            for (int k = 0; k < 16; ++k) oa += wo[k] * hb[k];
            if (j < 8) outp[(t - 1) * F_ + j] = oa;
        }
        float acc0 = xp[0], acc1 = xp[1], acc2 = xp[2], acc3 = xp[3];
#pragma unroll
        for (int k = 0; k < 16; ++k) {
            acc0 += wd[0][k] * hb[k];
            acc1 += wd[1][k] * hb[k];
            acc2 += wd[2][k] * hb[k];
            acc3 += wd[3][k] * hb[k];
        }
        const float ig = sigf(acc0);
        const float fg = sigf(acc1);
        const float gg = tanh_f(acc2);
        const float og = sigf(acc3);
        c = fg * c + ig * gg;
        h = og * tanh_f(c);
        __builtin_amdgcn_wave_barrier();
        hbuf[grp][j] = h;
        __builtin_amdgcn_wave_barrier();
    }
    // final timestep's output
    {
        float hb[16];
#pragma unroll
        for (int k = 0; k < 16; k += 4) {
            const float4 v = *(const float4*)&hbuf[grp][k];
            hb[k] = v.x; hb[k+1] = v.y; hb[k+2] = v.z; hb[k+3] = v.w;
        }
        float oa = obv;
#pragma unroll
        for (int k = 0; k < 16; ++k) oa += wo[k] * hb[k];
        if (j < 8) outp[(T_ - 1) * F_ + j] = oa;
    }
}

extern "C" void kernel_launch(void* const* d_in, const int* in_sizes, int n_in,
                              void* d_out, int out_size, void* d_ws, size_t ws_size,
                              hipStream_t stream) {
    (void)in_sizes; (void)n_in; (void)d_ws; (void)ws_size; (void)out_size;
    lstm_ae_kernel<<<dim3(B_ / 16), dim3(256), 0, stream>>>(
        (const float*)d_in[0],
        (const float*)d_in[1], (const float*)d_in[2],
        (const float*)d_in[3], (const float*)d_in[4],
        (const float*)d_in[5], (const float*)d_in[6],
        (const float*)d_in[7], (const float*)d_in[8],
        (const float*)d_in[9], (const float*)d_in[10],
        (float*)d_out);
}

// Round 2
// 406.078 us; speedup vs baseline: 1.2918x; 1.2918x over previous
//
#include <hip/hip_runtime.h>

#define B_ 4096
#define T_ 512
#define F_ 8
#define H_ 16

typedef float f32x2 __attribute__((ext_vector_type(2)));

__device__ __forceinline__ f32x2 pkfma(f32x2 a, f32x2 b, f32x2 c) {
    return __builtin_elementwise_fma(a, b, c);
}

__device__ __forceinline__ float sigf(float v) {
    return __builtin_amdgcn_rcpf(1.0f + __expf(-v));
}
// tanh(x) = 2*sigmoid(2x) - 1
__device__ __forceinline__ float tanh_f(float v) {
    return 2.0f * __builtin_amdgcn_rcpf(1.0f + __expf(-2.0f * v)) - 1.0f;
}

// Layout: 32 lanes per batch chain, 2 chains per wave, 8 per 256-thread block.
// 512 blocks -> 2048 waves -> 2 waves/SIMD (vs 1 in round 1) for latency hiding.
// Lane l (within chain) owns gate rows l (i/f: always sigmoid) and l+32
// (g: tanh for l<16, o: sigmoid for l>=16). Unit j = l&15 state (c,h) is
// replicated in lanes j and j+16. Gate exchange via shfl_xor(16); h broadcast
// via group LDS slot (same wave -> lockstep, wave_barrier pins ordering).
__global__ __launch_bounds__(256, 2) void lstm_ae_kernel(
    const float* __restrict__ x,
    const float* __restrict__ eWih, const float* __restrict__ eWhh,
    const float* __restrict__ ebih, const float* __restrict__ ebhh,
    const float* __restrict__ dWih, const float* __restrict__ dWhh,
    const float* __restrict__ dbih, const float* __restrict__ dbhh,
    const float* __restrict__ oW,   const float* __restrict__ ob,
    float* __restrict__ out)
{
    const int tid = threadIdx.x;
    const int ch  = tid >> 5;        // chain within block, 0..7
    const int l   = tid & 31;        // lane within chain
    const int j   = l & 15;          // hidden unit this lane replicates
    const bool lo = (l < 16);
    const int b   = blockIdx.x * 8 + ch;

    // chains 2w,2w+1 of a wave: bank sets 0..15 / 16..31 -> no write conflict
    __shared__ __align__(16) float hbuf[8][16];
    __shared__ __align__(16) float xsh[8][256];

    const int r0 = l;                // rows 0..31: i,f -> sigmoid
    const int r1 = l + 32;           // rows 32..63: g (tanh) / o (sigmoid)
    const float s1 = lo ? 2.0f : 1.0f;
    const float m1 = lo ? 2.0f : 1.0f;
    const float c1 = lo ? -1.0f : 0.0f;

    // ---------------- encoder weights (registers, packed pairs) -----------
    f32x2 wh0[8], wh1[8], wi0[4], wi1[4];
#pragma unroll
    for (int k = 0; k < 16; k += 4) {
        float4 v0 = *(const float4*)(eWhh + r0 * 16 + k);
        float4 v1 = *(const float4*)(eWhh + r1 * 16 + k);
        wh0[k/2]   = f32x2{v0.x, v0.y}; wh0[k/2+1] = f32x2{v0.z, v0.w};
        wh1[k/2]   = f32x2{v1.x, v1.y}; wh1[k/2+1] = f32x2{v1.z, v1.w};
    }
#pragma unroll
    for (int k = 0; k < 8; k += 4) {
        float4 v0 = *(const float4*)(eWih + r0 * 8 + k);
        float4 v1 = *(const float4*)(eWih + r1 * 8 + k);
        wi0[k/2]   = f32x2{v0.x, v0.y}; wi0[k/2+1] = f32x2{v0.z, v0.w};
        wi1[k/2]   = f32x2{v1.x, v1.y}; wi1[k/2+1] = f32x2{v1.z, v1.w};
    }
    const float bias0 = ebih[r0] + ebhh[r0];
    const float bias1 = ebih[r1] + ebhh[r1];

    float h = 0.0f, c = 0.0f;
    if (lo) hbuf[ch][j] = 0.0f;
    __builtin_amdgcn_wave_barrier();
    f32x2 hb[8];
#pragma unroll
    for (int p = 0; p < 8; ++p) hb[p] = f32x2{0.0f, 0.0f};

    const float* xb = x + (size_t)b * (T_ * F_);

    // ---------------- encoder ----------------
    for (int c0 = 0; c0 < T_; c0 += 32) {
        // stage 32 steps (256 floats) of x for this chain: 32 lanes x 2 float4
        {
            float4 v0 = *(const float4*)(xb + c0 * F_ + l * 4);
            float4 v1 = *(const float4*)(xb + c0 * F_ + 128 + l * 4);
            *(float4*)&xsh[ch][l * 4]       = v0;
            *(float4*)&xsh[ch][128 + l * 4] = v1;
        }
        __builtin_amdgcn_wave_barrier();
        for (int s = 0; s < 32; ++s) {
            float4 u0 = *(const float4*)&xsh[ch][s * F_];
            float4 u1 = *(const float4*)&xsh[ch][s * F_ + 4];
            f32x2 xv0 = f32x2{u0.x, u0.y}, xv1 = f32x2{u0.z, u0.w};
            f32x2 xv2 = f32x2{u1.x, u1.y}, xv3 = f32x2{u1.z, u1.w};

            f32x2 a0a = f32x2{bias0, 0.0f}, a0b = f32x2{0.0f, 0.0f};
            f32x2 a1a = f32x2{bias1, 0.0f}, a1b = f32x2{0.0f, 0.0f};
            a0a = pkfma(wi0[0], xv0, a0a); a0b = pkfma(wi0[1], xv1, a0b);
            a0a = pkfma(wi0[2], xv2, a0a); a0b = pkfma(wi0[3], xv3, a0b);
            a1a = pkfma(wi1[0], xv0, a1a); a1b = pkfma(wi1[1], xv1, a1b);
            a1a = pkfma(wi1[2], xv2, a1a); a1b = pkfma(wi1[3], xv3, a1b);
#pragma unroll
            for (int p = 0; p < 8; p += 2) {
                a0a = pkfma(wh0[p],   hb[p],   a0a);
                a0b = pkfma(wh0[p+1], hb[p+1], a0b);
                a1a = pkfma(wh1[p],   hb[p],   a1a);
                a1b = pkfma(wh1[p+1], hb[p+1], a1b);
            }
            f32x2 t0 = a0a + a0b; const float acc0 = t0.x + t0.y;
            f32x2 t1 = a1a + a1b; const float acc1 = t1.x + t1.y;

            const float a0 = sigf(acc0);
            const float a1 = m1 * __builtin_amdgcn_rcpf(1.0f + __expf(-s1 * acc1)) + c1;
            const float e0 = __shfl_xor(a0, 16, 64);
            const float e1 = __shfl_xor(a1, 16, 64);
            const float gi = lo ? a0 : e0;
            const float gf = lo ? e0 : a0;
            const float gg = lo ? a1 : e1;
            const float go = lo ? e1 : a1;
            c = gf * c + gi * gg;
            h = go * tanh_f(c);
            __builtin_amdgcn_wave_barrier();
            if (lo) hbuf[ch][j] = h;
            __builtin_amdgcn_wave_barrier();
            float4 q0 = *(const float4*)&hbuf[ch][0];
            float4 q1 = *(const float4*)&hbuf[ch][4];
            float4 q2 = *(const float4*)&hbuf[ch][8];
            float4 q3 = *(const float4*)&hbuf[ch][12];
            hb[0] = f32x2{q0.x, q0.y}; hb[1] = f32x2{q0.z, q0.w};
            hb[2] = f32x2{q1.x, q1.y}; hb[3] = f32x2{q1.z, q1.w};
            hb[4] = f32x2{q2.x, q2.y}; hb[5] = f32x2{q2.z, q2.w};
            hb[6] = f32x2{q3.x, q3.y}; hb[7] = f32x2{q3.z, q3.w};
        }
    }

    // ---------------- decoder weights + constant input projection ----------
    f32x2 wd0[8], wd1[8], wo2[8];
    float xp0, xp1;
    {
        f32x2 p0a = f32x2{dbih[r0] + dbhh[r0], 0.0f}, p0b = f32x2{0.0f, 0.0f};
        f32x2 p1a = f32x2{dbih[r1] + dbhh[r1], 0.0f}, p1b = f32x2{0.0f, 0.0f};
#pragma unroll
        for (int k = 0; k < 16; k += 4) {
            float4 v0 = *(const float4*)(dWih + r0 * 16 + k);
            float4 v1 = *(const float4*)(dWih + r1 * 16 + k);
            p0a = pkfma(f32x2{v0.x, v0.y}, hb[k/2],   p0a);
            p0b = pkfma(f32x2{v0.z, v0.w}, hb[k/2+1], p0b);
            p1a = pkfma(f32x2{v1.x, v1.y}, hb[k/2],   p1a);
            p1b = pkfma(f32x2{v1.z, v1.w}, hb[k/2+1], p1b);
        }
        f32x2 t0 = p0a + p0b; xp0 = t0.x + t0.y;
        f32x2 t1 = p1a + p1b; xp1 = t1.x + t1.y;
#pragma unroll
        for (int k = 0; k < 16; k += 4) {
            float4 v0 = *(const float4*)(dWhh + r0 * 16 + k);
            float4 v1 = *(const float4*)(dWhh + r1 * 16 + k);
            wd0[k/2]   = f32x2{v0.x, v0.y}; wd0[k/2+1] = f32x2{v0.z, v0.w};
            wd1[k/2]   = f32x2{v1.x, v1.y}; wd1[k/2+1] = f32x2{v1.z, v1.w};
        }
        const int r = l & 7;
#pragma unroll
        for (int k = 0; k < 16; k += 4) {
            float4 v = *(const float4*)(oW + r * 16 + k);
            wo2[k/2]   = f32x2{v.x, v.y}; wo2[k/2+1] = f32x2{v.z, v.w};
        }
    }
    const float obv = ob[l & 7];

    h = 0.0f; c = 0.0f;
    __builtin_amdgcn_wave_barrier();
    if (lo) hbuf[ch][j] = 0.0f;
    __builtin_amdgcn_wave_barrier();
#pragma unroll
    for (int p = 0; p < 8; ++p) hb[p] = f32x2{0.0f, 0.0f};

    float* outp = out + (size_t)b * (T_ * F_);

    // ---------------- decoder + fused output projection ----------------
    for (int t = 0; t < T_; ++t) {
        f32x2 a0a = f32x2{xp0, 0.0f}, a0b = f32x2{0.0f, 0.0f};
        f32x2 a1a = f32x2{xp1, 0.0f}, a1b = f32x2{0.0f, 0.0f};
#pragma unroll
        for (int p = 0; p < 8; p += 2) {
            a0a = pkfma(wd0[p],   hb[p],   a0a);
            a0b = pkfma(wd0[p+1], hb[p+1], a0b);
            a1a = pkfma(wd1[p],   hb[p],   a1a);
            a1b = pkfma(wd1[p+1], hb[p+1], a1b);
        }
        f32x2 t0 = a0a + a0b; const float acc0 = t0.x + t0.y;
        f32x2 t1 = a1a + a1b; const float acc1 = t1.x + t1.y;

        const float a0 = sigf(acc0);
        const float a1 = m1 * __builtin_amdgcn_rcpf(1.0f + __expf(-s1 * acc1)) + c1;
        const float e0 = __shfl_xor(a0, 16, 64);
        const float e1 = __shfl_xor(a1, 16, 64);
        const float gi = lo ? a0 : e0;
        const float gf = lo ? e0 : a0;
        const float gg = lo ? a1 : e1;
        const float go = lo ? e1 : a1;
        c = gf * c + gi * gg;
        h = go * tanh_f(c);
        __builtin_amdgcn_wave_barrier();
        if (lo) hbuf[ch][j] = h;
        __builtin_amdgcn_wave_barrier();
        float4 q0 = *(const float4*)&hbuf[ch][0];
        float4 q1 = *(const float4*)&hbuf[ch][4];
        float4 q2 = *(const float4*)&hbuf[ch][8];
        float4 q3 = *(const float4*)&hbuf[ch][12];
        hb[0] = f32x2{q0.x, q0.y}; hb[1] = f32x2{q0.z, q0.w};
        hb[2] = f32x2{q1.x, q1.y}; hb[3] = f32x2{q1.z, q1.w};
        hb[4] = f32x2{q2.x, q2.y}; hb[5] = f32x2{q2.z, q2.w};
        hb[6] = f32x2{q3.x, q3.y}; hb[7] = f32x2{q3.z, q3.w};

        // output projection from the just-updated h (feature l&7, x4 redundant)
        f32x2 oaa = f32x2{obv, 0.0f}, oab = f32x2{0.0f, 0.0f};
#pragma unroll
        for (int p = 0; p < 8; p += 2) {
            oaa = pkfma(wo2[p],   hb[p],   oaa);
            oab = pkfma(wo2[p+1], hb[p+1], oab);
        }
        f32x2 to = oaa + oab; const float oa = to.x + to.y;
        if (l < 8) outp[t * F_ + l] = oa;
    }
}

extern "C" void kernel_launch(void* const* d_in, const int* in_sizes, int n_in,
                              void* d_out, int out_size, void* d_ws, size_t ws_size,
                              hipStream_t stream) {
    (void)in_sizes; (void)n_in; (void)d_ws; (void)ws_size; (void)out_size;
    lstm_ae_kernel<<<dim3(B_ / 8), dim3(256), 0, stream>>>(
        (const float*)d_in[0],
        (const float*)d_in[1], (const float*)d_in[2],
        (const float*)d_in[3], (const float*)d_in[4],
        (const float*)d_in[5], (const float*)d_in[6],
        (const float*)d_in[7], (const float*)d_in[8],
        (const float*)d_in[9], (const float*)d_in[10],
        (float*)d_out);
}